// Round 8
// baseline (253.302 us; speedup 1.0000x reference)
//
#include <hip/hip_runtime.h>
#include <hip/hip_bf16.h>

#define NBANDS 5
#define BATCH  16
#define DIM    256
#define NNODE  64
#define SEQ    5

typedef __hip_bfloat16 bf16;
typedef unsigned short ushort_t;
typedef __attribute__((ext_vector_type(8))) short short8;   // 8 bf16 (4 VGPRs)
typedef __attribute__((ext_vector_type(4))) float float4v;  // 4 fp32 acc

#define MFMA __builtin_amdgcn_mfma_f32_16x16x32_bf16

__device__ __forceinline__ float bu2f(ushort_t u){
    bf16 h = *reinterpret_cast<bf16*>(&u);
    return __bfloat162float(h);
}
__device__ __forceinline__ ushort_t f2bu(float x){
    bf16 h = __float2bfloat16(x);
    return *reinterpret_cast<ushort_t*>(&h);
}
__device__ __forceinline__ float elu(float v){
    return (v > 0.f) ? v : (__expf(v) - 1.f);
}
__device__ __forceinline__ float sum8(const float* __restrict__ p, size_t i){
    float v = 0.f;
    #pragma unroll
    for (int q = 0; q < 8; ++q) v += p[(size_t)q*20480 + i];
    return v;
}

// ============ k_head: weight transpose+convert only (240 blocks) ============
__global__ void __launch_bounds__(256) k_head(
    const float* __restrict__ w1, const float* __restrict__ gw,
    ushort_t* __restrict__ w1bt, ushort_t* __restrict__ gwbt)
{
    int blk = blockIdx.x;
    int tid = threadIdx.x;
    __shared__ ushort_t tile[64][65];
    int inst = blk >> 4;
    int t = blk & 15;
    int r0 = (t>>2)*64, c0 = (t&3)*64;
    const float* src; ushort_t* dst;
    if (inst < 10){
        int k = inst>>1, half = inst&1;
        src = w1  + ((size_t)k*512 + half*256)*256;
        dst = w1bt+ ((size_t)k*512 + half*256)*256;
    } else {
        int k = inst-10;
        src = gw  + (size_t)k*65536;
        dst = gwbt+ (size_t)k*65536;
    }
    int jj = tid & 63, i4 = tid >> 6;
    for (int p=0;p<16;p++){
        int i = p*4 + i4;
        tile[i][jj] = f2bu(src[(size_t)(r0+i)*256 + c0 + jj]);
    }
    __syncthreads();
    for (int p=0;p<16;p++){
        int i = p*4 + i4;
        dst[(size_t)(c0+i)*256 + r0 + jj] = tile[jj][i];
    }
}

// ============ k_graph: fused per-(band,batch,i-eighth) pipeline =============
// 640 blocks x 512 thr, 8 output rows/block, LDS staging KEPT (R4's mistake
// was global operands). kb = blk % 80 keeps the 8 iq-siblings on one XCD.
__global__ void __launch_bounds__(512) k_graph(
    const float* __restrict__ feat,
    const ushort_t* __restrict__ w1bt, const float* __restrict__ b1,
    const float* __restrict__ w2, const float* __restrict__ b2arr,
    const float* __restrict__ l_adj_w, const float* __restrict__ l_pos_enc,
    const float* __restrict__ l_pf,
    const ushort_t* __restrict__ gwbt, const float* __restrict__ gb,
    const float* __restrict__ imp_w,
    float* __restrict__ out_local,
    float* __restrict__ scalew8, float* __restrict__ impw8)
{
    int kb = blockIdx.x % 80;
    int iq = blockIdx.x / 80;            // 0..7
    int k  = kb >> 4;
    int b  = kb & 15;
    int i0 = iq << 3;                    // 8 rows per block
    int tid = threadIdx.x;
    int w = tid >> 6, lane = tid & 63, c16 = lane & 15, quad = lane >> 4;

    __shared__ __align__(16) ushort_t Ubuf[64*266 + 8];
    __shared__ __align__(16) ushort_t as[8][260];
    __shared__ __align__(16) ushort_t cs[16][72];    // rows 8..15 zero
    ushort_t* ys = Ubuf;                             // aliased after dyn

    const float* src = feat + ((size_t)b*NBANDS + k)*DIM*NNODE;

    float sbias2 = b2arr[k];
    // inline sbase row i0+w (one row per wave)
    float sb;
    {
        float pf = l_pf[k];
        float aw = l_adj_w[(k*NNODE + i0 + w)*NNODE + lane];
        float pe = l_pos_enc[(k*NNODE + i0 + w)*NNODE + lane];
        float m1 = aw, m2 = pe;
        for (int o=32;o>0;o>>=1){
            m1 = fmaxf(m1, __shfl_xor(m1,o,64));
            m2 = fmaxf(m2, __shfl_xor(m2,o,64));
        }
        float e1 = __expf(aw-m1), e2 = __expf(pe-m2);
        float s1 = e1, s2 = e2;
        for (int o=32;o>0;o>>=1){
            s1 += __shfl_xor(s1,o,64);
            s2 += __shfl_xor(s2,o,64);
        }
        sb = e1/s1 + pf*(e2/s2);
    }

    // staging: packed short8, ds_write_b128
    #pragma unroll
    for (int u = 0; u < 4; ++u){
        int t = u*512 + tid;
        int n = t & 63;
        int d0 = (t >> 6) * 8;
        short8 pk;
        #pragma unroll
        for (int i = 0; i < 8; ++i) pk[i] = (short)f2bu(src[(size_t)(d0+i)*NNODE + n]);
        *reinterpret_cast<short8*>(&Ubuf[(size_t)n*264 + d0]) = pk;
    }
    // zero cs pad rows 8..15 (read as zero A-rows in y GEMM)
    if (tid < 512) cs[8 + (tid>>6)][tid & 63] = 0;
    __syncthreads();

    int col0 = w*32 + c16;
    int col1 = col0 + 16;

    // ---- ab GEMM: a 8 valid rows (16-row tile, clamped), b all 64 rows -----
    int arow = i0 + c16; if (arow > 63) arow = 63;
    const ushort_t* Ba = w1bt + (size_t)k*512*DIM;
    const ushort_t* Bb = Ba + 256*DIM;
    float4v z = {0.f,0.f,0.f,0.f};
    float4v aA0=z, aA1=z;
    float4v aB00=z,aB01=z,aB10=z,aB11=z,aB20=z,aB21=z,aB30=z,aB31=z;
    #pragma unroll
    for (int ks = 0; ks < 8; ++ks){
        int ko = ks*32 + quad*8;
        short8 fa = *reinterpret_cast<const short8*>(&Ubuf[arow*264 + ko]);
        short8 f0 = *reinterpret_cast<const short8*>(&Ubuf[( 0 + c16)*264 + ko]);
        short8 f1 = *reinterpret_cast<const short8*>(&Ubuf[(16 + c16)*264 + ko]);
        short8 f2 = *reinterpret_cast<const short8*>(&Ubuf[(32 + c16)*264 + ko]);
        short8 f3 = *reinterpret_cast<const short8*>(&Ubuf[(48 + c16)*264 + ko]);
        short8 wa0 = *reinterpret_cast<const short8*>(Ba + (size_t)col0*DIM + ko);
        short8 wa1 = *reinterpret_cast<const short8*>(Ba + (size_t)col1*DIM + ko);
        short8 wb0 = *reinterpret_cast<const short8*>(Bb + (size_t)col0*DIM + ko);
        short8 wb1 = *reinterpret_cast<const short8*>(Bb + (size_t)col1*DIM + ko);
        aA0  = MFMA(fa, wa0, aA0, 0,0,0);
        aA1  = MFMA(fa, wa1, aA1, 0,0,0);
        aB00 = MFMA(f0, wb0, aB00, 0,0,0);
        aB01 = MFMA(f0, wb1, aB01, 0,0,0);
        aB10 = MFMA(f1, wb0, aB10, 0,0,0);
        aB11 = MFMA(f1, wb1, aB11, 0,0,0);
        aB20 = MFMA(f2, wb0, aB20, 0,0,0);
        aB21 = MFMA(f2, wb1, aB21, 0,0,0);
        aB30 = MFMA(f3, wb0, aB30, 0,0,0);
        aB31 = MFMA(f3, wb1, aB31, 0,0,0);
    }
    __syncthreads();   // xtb reads done; Ubuf reused as b-dyn region (@266)
    {
        float bias0 = b1[k*DIM + col0];
        float bias1 = b1[k*DIM + col1];
        int r0 = quad*4;
        if (quad < 2){
            #pragma unroll
            for (int r = 0; r < 4; ++r){
                as[r0 + r][col0] = f2bu(aA0[r] + bias0);
                as[r0 + r][col1] = f2bu(aA1[r] + bias1);
            }
        }
        #pragma unroll
        for (int r = 0; r < 4; ++r){
            Ubuf[( 0 + r0 + r)*266 + col0] = f2bu(aB00[r]);
            Ubuf[( 0 + r0 + r)*266 + col1] = f2bu(aB01[r]);
            Ubuf[(16 + r0 + r)*266 + col0] = f2bu(aB10[r]);
            Ubuf[(16 + r0 + r)*266 + col1] = f2bu(aB11[r]);
            Ubuf[(32 + r0 + r)*266 + col0] = f2bu(aB20[r]);
            Ubuf[(32 + r0 + r)*266 + col1] = f2bu(aB21[r]);
            Ubuf[(48 + r0 + r)*266 + col0] = f2bu(aB30[r]);
            Ubuf[(48 + r0 + r)*266 + col1] = f2bu(aB31[r]);
        }
    }
    __syncthreads();

    // ---- dyn + comb: wave w owns row i0+w; lane = j -------------------------
    {
        const ushort_t* bd = Ubuf + 266*lane;
        const ushort_t* ap = &as[w][0];
        const float* w2p = w2 + k*DIM;
        float acc = 0.f;
        #pragma unroll 4
        for (int dd = 0; dd < 64; ++dd){
            unsigned int blo = *reinterpret_cast<const unsigned int*>(bd + dd*4);
            unsigned int bhi = *reinterpret_cast<const unsigned int*>(bd + dd*4 + 2);
            ushort4 a0 = *reinterpret_cast<const ushort4*>(ap + dd*4);   // broadcast
            float4 wv  = *reinterpret_cast<const float4*>(w2p + dd*4);
            float bx = bu2f((ushort_t)(blo & 0xffffu));
            float by = bu2f((ushort_t)(blo >> 16));
            float bz = bu2f((ushort_t)(bhi & 0xffffu));
            float bq = bu2f((ushort_t)(bhi >> 16));
            acc += elu(bu2f(a0.x)+bx)*wv.x + elu(bu2f(a0.y)+by)*wv.y
                 + elu(bu2f(a0.z)+bz)*wv.z + elu(bu2f(a0.w)+bq)*wv.w;
        }
        float sg = 1.f/(1.f + __expf(-(acc + sbias2)));
        float val = sb + sg;
        float m = val;
        for (int o=32;o>0;o>>=1) m = fmaxf(m, __shfl_xor(m,o,64));
        float e = __expf(val - m);
        float s = e;
        for (int o=32;o>0;o>>=1) s += __shfl_xor(s,o,64);
        cs[w][lane] = f2bu(e/s);
    }
    __syncthreads();   // b-rows dead; Ubuf reused as ys (@264)

    // ---- y GEMM: y[8][256] = comb[8][64] @ xt[64][256] ----------------------
    {
        float4v aY0 = z, aY1 = z;
        #pragma unroll
        for (int ks = 0; ks < 2; ++ks){
            int ko = ks*32 + quad*8;
            short8 af = *reinterpret_cast<const short8*>(&cs[c16][ko]);
            const float* f0p = src + (size_t)col0*NNODE + ko;
            const float* f1p = src + (size_t)col1*NNODE + ko;
            float4 x0 = *reinterpret_cast<const float4*>(f0p);
            float4 x1 = *reinterpret_cast<const float4*>(f0p+4);
            float4 y0 = *reinterpret_cast<const float4*>(f1p);
            float4 y1 = *reinterpret_cast<const float4*>(f1p+4);
            short8 bf0, bf1;
            bf0[0]=(short)f2bu(x0.x); bf0[1]=(short)f2bu(x0.y); bf0[2]=(short)f2bu(x0.z); bf0[3]=(short)f2bu(x0.w);
            bf0[4]=(short)f2bu(x1.x); bf0[5]=(short)f2bu(x1.y); bf0[6]=(short)f2bu(x1.z); bf0[7]=(short)f2bu(x1.w);
            bf1[0]=(short)f2bu(y0.x); bf1[1]=(short)f2bu(y0.y); bf1[2]=(short)f2bu(y0.z); bf1[3]=(short)f2bu(y0.w);
            bf1[4]=(short)f2bu(y1.x); bf1[5]=(short)f2bu(y1.y); bf1[6]=(short)f2bu(y1.z); bf1[7]=(short)f2bu(y1.w);
            aY0 = MFMA(af, bf0, aY0, 0,0,0);
            aY1 = MFMA(af, bf1, aY1, 0,0,0);
        }
        #pragma unroll
        for (int r=0;r<4;++r){
            ys[(quad*4 + r)*264 + col0] = (quad < 2) ? f2bu(aY0[r]) : (ushort_t)0;
            ys[(quad*4 + r)*264 + col1] = (quad < 2) ? f2bu(aY1[r]) : (ushort_t)0;
        }
    }
    __syncthreads();

    // ---- gcn GEMM + fused scale/importance partial reductions ---------------
    {
        float4v aG0 = z, aG1 = z;
        const ushort_t* Bg = gwbt + (size_t)k*DIM*DIM;
        #pragma unroll
        for (int ks = 0; ks < 8; ++ks){
            int ko = ks*32 + quad*8;
            short8 af = *reinterpret_cast<const short8*>(&ys[c16*264 + ko]);
            short8 g0 = *reinterpret_cast<const short8*>(Bg + (size_t)col0*DIM + ko);
            short8 g1 = *reinterpret_cast<const short8*>(Bg + (size_t)col1*DIM + ko);
            aG0 = MFMA(af, g0, aG0, 0,0,0);
            aG1 = MFMA(af, g1, aG1, 0,0,0);
        }
        int nb = i0 + quad*4;
        int nbc = (quad < 2) ? nb : i0;          // clamp for dead lanes
        float iw0 = imp_w[k*NNODE + nbc + 0];
        float iw1 = imp_w[k*NNODE + nbc + 1];
        float iw2 = imp_w[k*NNODE + nbc + 2];
        float iw3 = imp_w[k*NNODE + nbc + 3];
        size_t obase = ((size_t)b*NBANDS + k)*DIM;

        float bias0 = gb[k*DIM + col0];
        float v0 = aG0[0]+bias0, v1 = aG0[1]+bias0, v2 = aG0[2]+bias0, v3 = aG0[3]+bias0;
        if (quad < 2){
            *reinterpret_cast<float4*>(&out_local[(obase + col0)*NNODE + nb]) =
                make_float4(v0,v1,v2,v3);
        }
        float s  = (quad < 2) ? (v0+v1+v2+v3) : 0.f;
        float di = (quad < 2) ? (v0*iw0 + v1*iw1 + v2*iw2 + v3*iw3) : 0.f;
        s  += __shfl_xor(s,16,64);  s  += __shfl_xor(s,32,64);
        di += __shfl_xor(di,16,64); di += __shfl_xor(di,32,64);
        if (quad == 0){
            size_t o = (size_t)iq*20480 + ((size_t)b*SEQ + k)*DIM + col0;
            scalew8[o] = s;
            impw8[o]   = di;
        }

        float bias1 = gb[k*DIM + col1];
        v0 = aG1[0]+bias1; v1 = aG1[1]+bias1; v2 = aG1[2]+bias1; v3 = aG1[3]+bias1;
        if (quad < 2){
            *reinterpret_cast<float4*>(&out_local[(obase + col1)*NNODE + nb]) =
                make_float4(v0,v1,v2,v3);
        }
        s  = (quad < 2) ? (v0+v1+v2+v3) : 0.f;
        di = (quad < 2) ? (v0*iw0 + v1*iw1 + v2*iw2 + v3*iw3) : 0.f;
        s  += __shfl_xor(s,16,64);  s  += __shfl_xor(s,32,64);
        di += __shfl_xor(di,16,64); di += __shfl_xor(di,32,64);
        if (quad == 0){
            size_t o = (size_t)iq*20480 + ((size_t)b*SEQ + k)*DIM + col1;
            scalew8[o] = s;
            impw8[o]   = di;
        }
    }
}

// -------- block LayerNorm over 256 elems, 1024 threads (4x redundancy) ------
__device__ __forceinline__ float block_ln1024(float v, int tid, float* red, float g, float bb)
{
    float s = v;
    for (int o=32;o>0;o>>=1) s += __shfl_xor(s,o,64);
    int wave = tid>>6, lane = tid&63;
    if (lane==0) red[wave] = s;
    __syncthreads();
    float tot = 0.f;
    #pragma unroll
    for (int q=0;q<16;++q) tot += red[q];
    float mean = tot * (1.f/1024.f);
    float c = v - mean;
    float q2 = c*c;
    for (int o=32;o>0;o>>=1) q2 += __shfl_xor(q2,o,64);
    __syncthreads();
    if (lane==0) red[wave] = q2;
    __syncthreads();
    tot = 0.f;
    #pragma unroll
    for (int q=0;q<16;++q) tot += red[q];
    float var = tot * (1.f/1024.f);
    return c * rsqrtf(var + 1e-5f) * g + bb;
}

// ============ k_attnmlp: per-row fused tail, 1024 thr, float4 GEMVs =========
// qkv -> MHA -> proj+res+LN1 -> mlp1+gelu -> mlp2+res+LN2 -> gab.
// Every GEMV: 4 cols/thread (float4 weight loads) x k-slices + LDS reduce.
__global__ void __launch_bounds__(1024) k_attnmlp(
    const float* __restrict__ scalew8,
    const float* __restrict__ qkv_w, const float* __restrict__ qkv_b,
    const float* __restrict__ attn_ow, const float* __restrict__ attn_ob,
    const float* __restrict__ ln1_g, const float* __restrict__ ln1_b,
    const float* __restrict__ mlp_w1, const float* __restrict__ mlp_b1,
    const float* __restrict__ mlp_w2, const float* __restrict__ mlp_b2,
    const float* __restrict__ ln2_g, const float* __restrict__ ln2_b,
    const float* __restrict__ gw1, const float* __restrict__ gb1,
    float* __restrict__ sew, float* __restrict__ gaw, float* __restrict__ gbw)
{
    int r = blockIdx.x;                 // b*SEQ + i
    int b = r / SEQ, i = r % SEQ;
    int tid = threadIdx.x;

    __shared__ __align__(16) float xs5[SEQ][260];
    __shared__ __align__(16) float kv[2*SEQ][260];   // k rows 0..4, v rows 5..9
    __shared__ __align__(16) float qi[256];
    __shared__ __align__(16) float xo[256];
    __shared__ __align__(16) float h1[256];
    __shared__ __align__(16) float se[256];
    __shared__ __align__(16) float mh[1024];
    __shared__ __align__(16) float parts[4096];
    __shared__ float red[16];

    // A0: fold scale partials for all rows of batch b
    for (int t = tid; t < SEQ*DIM; t += 1024){
        int j = t >> 8, d = t & 255;
        xs5[j][d] = sum8(scalew8, ((size_t)b*SEQ + j)*DIM + d) * (1.f/64.f);
    }
    __syncthreads();

    // A1: qkv — q (row i, 64 groups) + k,v (5 rows x 128 groups) = 704 tasks
    if (tid < 704){
        float4 acc;
        if (tid < 64){
            int cg = tid*4;
            acc = *reinterpret_cast<const float4*>(&qkv_b[cg]);
            const float* wp = qkv_w + cg;
            const float* xp = xs5[i];
            #pragma unroll 4
            for (int d = 0; d < 256; ++d){
                float4 w4 = *reinterpret_cast<const float4*>(wp + (size_t)d*768);
                float xd = xp[d];
                acc.x += w4.x*xd; acc.y += w4.y*xd; acc.z += w4.z*xd; acc.w += w4.w*xd;
            }
            *reinterpret_cast<float4*>(&qi[cg]) = acc;
        } else {
            int t2 = tid - 64;
            int j = t2 >> 7;                 // 0..4
            int col = 256 + (t2 & 127)*4;    // 256..764
            acc = *reinterpret_cast<const float4*>(&qkv_b[col]);
            const float* wp = qkv_w + col;
            const float* xp = xs5[j];
            #pragma unroll 4
            for (int d = 0; d < 256; ++d){
                float4 w4 = *reinterpret_cast<const float4*>(wp + (size_t)d*768);
                float xd = xp[d];
                acc.x += w4.x*xd; acc.y += w4.y*xd; acc.z += w4.z*xd; acc.w += w4.w*xd;
            }
            float* dst = (col < 512) ? &kv[j][col-256] : &kv[SEQ + j][col-512];
            *reinterpret_cast<float4*>(dst) = acc;
        }
    }
    __syncthreads();

    // A2: attention for row i (waves 0..3 = heads)
    if (tid < 256){
        int h = tid >> 6, l = tid & 63;
        float qv = qi[h*64 + l];
        float pj[SEQ];
        #pragma unroll
        for (int j=0;j<SEQ;j++){
            float p = qv * kv[j][h*64 + l];
            for (int o=32;o>0;o>>=1) p += __shfl_xor(p,o,64);
            pj[j] = p * 0.125f;
        }
        float m = pj[0];
        #pragma unroll
        for (int j=1;j<SEQ;j++) m = fmaxf(m, pj[j]);
        float ss = 0.f;
        #pragma unroll
        for (int j=0;j<SEQ;j++){ pj[j] = __expf(pj[j]-m); ss += pj[j]; }
        float inv = 1.f/ss;
        float o = 0.f;
        #pragma unroll
        for (int j=0;j<SEQ;j++) o += pj[j]*inv * kv[SEQ + j][h*64 + l];
        xo[h*64 + l] = o;
    }
    __syncthreads();

    // A3: proj — 64 col-groups x 16 k-slices (16 dims each)
    {
        int cg = (tid & 63)*4, ks = tid >> 6;
        const float* wp = attn_ow + (size_t)(ks*16)*DIM + cg;
        float4 acc = {0.f,0.f,0.f,0.f};
        #pragma unroll
        for (int d = 0; d < 16; ++d){
            float4 w4 = *reinterpret_cast<const float4*>(wp + (size_t)d*DIM);
            float xd = xo[ks*16 + d];
            acc.x += w4.x*xd; acc.y += w4.y*xd; acc.z += w4.z*xd; acc.w += w4.w*xd;
        }
        *reinterpret_cast<float4*>(&parts[ks*256 + cg]) = acc;
    }
    __syncthreads();
    if (tid < 256){
        float v = attn_ob[tid];
        #pragma unroll
        for (int q=0;q<16;++q) v += parts[q*256 + tid];
        h1[tid] = v + xs5[i][tid];
    }
    __syncthreads();
    {
        int c = tid & 255;
        float hh = block_ln1024(h1[c], tid, red, ln1_g[c], ln1_b[c]);
        __syncthreads();
        if (tid < 256) h1[c] = hh;
    }
    __syncthreads();

    // A4: mlp1+gelu — 256 col-groups x 4 k-slices (64 dims each)
    {
        int cg = (tid & 255)*4, ks = tid >> 8;
        const float* wp = mlp_w1 + (size_t)(ks*64)*1024 + cg;
        float4 acc = {0.f,0.f,0.f,0.f};
        #pragma unroll 8
        for (int d = 0; d < 64; ++d){
            float4 w4 = *reinterpret_cast<const float4*>(wp + (size_t)d*1024);
            float xd = h1[ks*64 + d];
            acc.x += w4.x*xd; acc.y += w4.y*xd; acc.z += w4.z*xd; acc.w += w4.w*xd;
        }
        *reinterpret_cast<float4*>(&parts[ks*1024 + cg]) = acc;
    }
    __syncthreads();
    {
        float v = mlp_b1[tid] + parts[tid] + parts[1024+tid] + parts[2048+tid] + parts[3072+tid];
        mh[tid] = 0.5f*v*(1.f + erff(v*0.70710678118654752f));
    }
    __syncthreads();

    // A5: mlp2 — 64 col-groups x 16 k-slices (64 dims each)
    {
        int cg = (tid & 63)*4, ks = tid >> 6;
        const float* wp = mlp_w2 + (size_t)(ks*64)*DIM + cg;
        float4 acc = {0.f,0.f,0.f,0.f};
        #pragma unroll 8
        for (int d = 0; d < 64; ++d){
            float4 w4 = *reinterpret_cast<const float4*>(wp + (size_t)d*DIM);
            float xd = mh[ks*64 + d];
            acc.x += w4.x*xd; acc.y += w4.y*xd; acc.z += w4.z*xd; acc.w += w4.w*xd;
        }
        *reinterpret_cast<float4*>(&parts[ks*256 + cg]) = acc;
    }
    __syncthreads();
    if (tid < 256){
        float v = mlp_b2[tid];
        #pragma unroll
        for (int q=0;q<16;++q) v += parts[q*256 + tid];
        se[tid] = v + h1[tid];
    }
    __syncthreads();
    {
        int c = tid & 255;
        float hh = block_ln1024(se[c], tid, red, ln2_g[c], ln2_b[c]);
        __syncthreads();
        if (tid < 256){ se[c] = hh; sew[(size_t)r*DIM + c] = hh; }
    }
    __syncthreads();

    // A6: gab — 128 col-groups (512 cols: ga|gb) x 8 k-slices (32 dims each)
    {
        int oc = (tid & 127)*4, ks = tid >> 7;
        int mat = oc >> 8, cc = oc & 255;
        const float* wp = gw1 + ((size_t)mat*DIM + ks*32)*DIM + cc;
        float4 acc = {0.f,0.f,0.f,0.f};
        #pragma unroll 8
        for (int d = 0; d < 32; ++d){
            float4 w4 = *reinterpret_cast<const float4*>(wp + (size_t)d*DIM);
            float xd = se[ks*32 + d];
            acc.x += w4.x*xd; acc.y += w4.y*xd; acc.z += w4.z*xd; acc.w += w4.w*xd;
        }
        *reinterpret_cast<float4*>(&parts[ks*512 + (tid & 127)*4]) = acc;
    }
    __syncthreads();
    if (tid < 512){
        float v = 0.f;
        #pragma unroll
        for (int q=0;q<8;++q) v += parts[q*512 + tid];
        int mat = tid >> 8, cc = tid & 255;
        if (mat == 0) gaw[(size_t)r*DIM + cc] = gb1[cc] + v;
        else          gbw[(size_t)r*DIM + cc] = v;
    }
}

// ---- gout with inline gbase + gadj + gmix + final modulation ---------------
__global__ void __launch_bounds__(256) k_goutfin(const float* __restrict__ gaw,
                        const float* __restrict__ gbw,
                        const float* __restrict__ gw2, const float* __restrict__ gb2,
                        const float* __restrict__ g_adj_w,
                        const float* __restrict__ g_pos_enc,
                        const float* __restrict__ g_pf,
                        const float* __restrict__ sew,
                        const float* __restrict__ ggw, const float* __restrict__ ggb,
                        const float* __restrict__ impw8, const float* __restrict__ imp_b,
                        float* __restrict__ out0, float* __restrict__ out_gadj)
{
    int row = blockIdx.x / 4;            // b*SEQ + i
    int n0 = (blockIdx.x % 4) * 64;
    int b = row / SEQ, i = row % SEQ;
    int tid = threadIdx.x;
    int wave = tid >> 6, lane = tid & 63;
    __shared__ float dyn_s[SEQ];
    __shared__ float xs[DIM];
    __shared__ float part[4][64];
    for (int j = wave; j < SEQ; j += 4){
        const float* gar = gaw + (size_t)row*DIM;
        const float* gbr = gbw + ((size_t)b*SEQ + j)*DIM;
        float acc = 0.f;
        #pragma unroll
        for (int m=0;m<4;m++){
            int dd = lane + m*64;
            float v = gar[dd] + gbr[dd];
            acc += elu(v) * gw2[dd];
        }
        for (int o=32;o>0;o>>=1) acc += __shfl_xor(acc,o,64);
        if (lane==0) dyn_s[j] = acc;
    }
    __syncthreads();
    float gc[SEQ];
    {
        float basei[SEQ];
        {
            float pf = g_pf[0];
            float r1[SEQ], r2[SEQ];
            float m1=-1e30f, m2=-1e30f;
            #pragma unroll
            for (int j=0;j<SEQ;j++){
                r1[j]=g_adj_w[i*SEQ+j]; r2[j]=g_pos_enc[i*SEQ+j];
                m1=fmaxf(m1,r1[j]); m2=fmaxf(m2,r2[j]);
            }
            float s1=0.f,s2=0.f;
            #pragma unroll
            for (int j=0;j<SEQ;j++){ r1[j]=__expf(r1[j]-m1); r2[j]=__expf(r2[j]-m2); s1+=r1[j]; s2+=r2[j]; }
            #pragma unroll
            for (int j=0;j<SEQ;j++) basei[j] = r1[j]/s1 + pf*(r2[j]/s2);
        }
        float sb2 = gb2[0];
        float m = -1e30f;
        #pragma unroll
        for (int j=0;j<SEQ;j++){
            float sg = 1.f/(1.f+__expf(-(dyn_s[j]+sb2)));
            gc[j] = basei[j] + sg;
            m = fmaxf(m, gc[j]);
        }
        float ssum=0.f;
        #pragma unroll
        for (int j=0;j<SEQ;j++){ gc[j]=__expf(gc[j]-m); ssum+=gc[j]; }
        float inv = 1.f/ssum;
        #pragma unroll
        for (int j=0;j<SEQ;j++) gc[j] *= inv;
    }
    if (n0 == 0 && tid < SEQ) out_gadj[((size_t)b*SEQ+i)*SEQ + tid] = gc[tid];
    float t = 0.f;
    #pragma unroll
    for (int j=0;j<SEQ;j++) t += gc[j]*sew[((size_t)b*SEQ + j)*DIM + tid];
    xs[tid] = t;
    __syncthreads();
    int c = tid & 63, s = tid >> 6;
    const float* wp = ggw + (size_t)(s*64)*DIM + n0 + c;
    const float* xp = xs + s*64;
    float acc = 0.f;
    #pragma unroll 8
    for (int k=0;k<64;++k) acc += xp[k] * wp[(size_t)k*DIM];
    part[s][c] = acc;
    __syncthreads();
    if (s == 0){
        float g = ggb[n0+c] + part[0][c]+part[1][c]+part[2][c]+part[3][c];
        size_t o = (size_t)row*DIM + n0 + c;
        float imps = sum8(impw8, o);
        out0[o] = g * imps + imp_b[i];
    }
}

extern "C" void kernel_launch(void* const* d_in, const int* in_sizes, int n_in,
                              void* d_out, int out_size, void* d_ws, size_t ws_size,
                              hipStream_t stream)
{
    const float* feature      = (const float*)d_in[0];
    const float* l_adj_w      = (const float*)d_in[1];
    const float* l_sim_w1     = (const float*)d_in[2];
    const float* l_sim_b1     = (const float*)d_in[3];
    const float* l_sim_w2     = (const float*)d_in[4];
    const float* l_sim_b2     = (const float*)d_in[5];
    const float* l_pos_factor = (const float*)d_in[6];
    const float* l_pos_enc    = (const float*)d_in[7];
    const float* l_gcn_w      = (const float*)d_in[8];
    const float* l_gcn_b      = (const float*)d_in[9];
    const float* g_adj_w      = (const float*)d_in[10];
    const float* g_sim_w1     = (const float*)d_in[11];
    const float* g_sim_b1     = (const float*)d_in[12];
    const float* g_sim_w2     = (const float*)d_in[13];
    const float* g_sim_b2     = (const float*)d_in[14];
    const float* g_pos_factor = (const float*)d_in[15];
    const float* g_pos_enc    = (const float*)d_in[16];
    const float* g_gcn_w      = (const float*)d_in[17];
    const float* g_gcn_b      = (const float*)d_in[18];
    const float* qkv_w        = (const float*)d_in[19];
    const float* qkv_b        = (const float*)d_in[20];
    const float* attn_ow      = (const float*)d_in[21];
    const float* attn_ob      = (const float*)d_in[22];
    const float* ln1_g        = (const float*)d_in[23];
    const float* ln1_b        = (const float*)d_in[24];
    const float* ln2_g        = (const float*)d_in[25];
    const float* ln2_b        = (const float*)d_in[26];
    const float* mlp_w1       = (const float*)d_in[27];
    const float* mlp_b1       = (const float*)d_in[28];
    const float* mlp_w2       = (const float*)d_in[29];
    const float* mlp_b2       = (const float*)d_in[30];
    const float* imp_w        = (const float*)d_in[31];
    const float* imp_b        = (const float*)d_in[32];

    float* out0      = (float*)d_out;
    float* out_gadj  = out0 + (size_t)BATCH*NBANDS*DIM;
    float* out_local = out_gadj + (size_t)BATCH*NBANDS*NBANDS;

    ushort_t* w1bt = (ushort_t*)d_ws;                               // 5*512*256
    ushort_t* gwbt = w1bt + (size_t)NBANDS*512*DIM;                 // 5*256*256
    float* fp = (float*)(gwbt + (size_t)NBANDS*DIM*DIM);
    float* scalew8 = fp; fp += 8*BATCH*SEQ*DIM;
    float* impw8   = fp; fp += 8*BATCH*SEQ*DIM;
    float* sew     = fp; fp += BATCH*SEQ*DIM;
    float* gaw     = fp; fp += BATCH*SEQ*DIM;
    float* gbw     = fp; fp += BATCH*SEQ*DIM;

    const int ROWS = BATCH*SEQ;   // 80

    k_head<<<240, 256, 0, stream>>>(l_sim_w1, l_gcn_w, w1bt, gwbt);
    k_graph<<<NBANDS*BATCH*8, 512, 0, stream>>>(feature, w1bt, l_sim_b1,
                                    l_sim_w2, l_sim_b2,
                                    l_adj_w, l_pos_enc, l_pos_factor,
                                    gwbt, l_gcn_b, imp_w,
                                    out_local, scalew8, impw8);
    k_attnmlp<<<ROWS, 1024, 0, stream>>>(scalew8, qkv_w, qkv_b,
                                    attn_ow, attn_ob, ln1_g, ln1_b,
                                    mlp_w1, mlp_b1, mlp_w2, mlp_b2,
                                    ln2_g, ln2_b, g_sim_w1, g_sim_b1,
                                    sew, gaw, gbw);
    k_goutfin<<<ROWS*4, 256, 0, stream>>>(gaw, gbw, g_sim_w2, g_sim_b2,
                                    g_adj_w, g_pos_enc, g_pos_factor,
                                    sew, g_gcn_w, g_gcn_b, impw8, imp_b,
                                    out0, out_gadj);
}

// Round 9
// 212.559 us; speedup vs baseline: 1.1917x; 1.1917x over previous
//
#include <hip/hip_runtime.h>
#include <hip/hip_bf16.h>

#define NBANDS 5
#define BATCH  16
#define DIM    256
#define NNODE  64
#define SEQ    5

typedef __hip_bfloat16 bf16;
typedef unsigned short ushort_t;
typedef __attribute__((ext_vector_type(8))) short short8;   // 8 bf16 (4 VGPRs)
typedef __attribute__((ext_vector_type(4))) float float4v;  // 4 fp32 acc

#define MFMA __builtin_amdgcn_mfma_f32_16x16x32_bf16

__device__ __forceinline__ float bu2f(ushort_t u){
    bf16 h = *reinterpret_cast<bf16*>(&u);
    return __bfloat162float(h);
}
__device__ __forceinline__ ushort_t f2bu(float x){
    bf16 h = __float2bfloat16(x);
    return *reinterpret_cast<ushort_t*>(&h);
}
__device__ __forceinline__ float elu(float v){
    return (v > 0.f) ? v : (__expf(v) - 1.f);
}
__device__ __forceinline__ float sum4(const float* __restrict__ p, size_t i){
    return p[i] + p[20480 + i] + p[40960 + i] + p[61440 + i];
}

// ============ k_head: softmax bases + MFMA weight prep (bf16 transpose) =====
__global__ void __launch_bounds__(256) k_head(
    const float* __restrict__ l_adj_w, const float* __restrict__ l_pos_enc,
    const float* __restrict__ l_pf,
    const float* __restrict__ g_adj_w, const float* __restrict__ g_pos_enc,
    const float* __restrict__ g_pf,
    float* __restrict__ sbase, float* __restrict__ gbase,
    const float* __restrict__ w1, const float* __restrict__ gw,
    ushort_t* __restrict__ w1bt, ushort_t* __restrict__ gwbt)
{
    int blk = blockIdx.x;
    int tid = threadIdx.x;
    __shared__ ushort_t tile[64][65];

    if (blk < 80) {
        int r = blk*4 + (tid>>6);
        int k = r >> 6, i = r & 63;
        int t = tid & 63;
        float aw = l_adj_w[(k*NNODE + i)*NNODE + t];
        float pe = l_pos_enc[(k*NNODE + i)*NNODE + t];
        float m1 = aw, m2 = pe;
        for (int o=32;o>0;o>>=1){ m1 = fmaxf(m1, __shfl_xor(m1,o,64)); m2 = fmaxf(m2, __shfl_xor(m2,o,64)); }
        float e1 = __expf(aw-m1), e2 = __expf(pe-m2);
        float s1=e1, s2=e2;
        for (int o=32;o>0;o>>=1){ s1 += __shfl_xor(s1,o,64); s2 += __shfl_xor(s2,o,64); }
        float pf = l_pf[k];
        sbase[(k*NNODE+i)*NNODE + t] = e1/s1 + pf*(e2/s2);
    } else if (blk == 80) {
        if (tid < NBANDS) {
            int i = tid;
            float r1[NBANDS], r2[NBANDS];
            float m1=-1e30f, m2=-1e30f;
            for (int j=0;j<NBANDS;j++){
                r1[j]=g_adj_w[i*NBANDS+j]; r2[j]=g_pos_enc[i*NBANDS+j];
                m1=fmaxf(m1,r1[j]); m2=fmaxf(m2,r2[j]);
            }
            float s1=0.f,s2=0.f;
            for (int j=0;j<NBANDS;j++){ r1[j]=__expf(r1[j]-m1); r2[j]=__expf(r2[j]-m2); s1+=r1[j]; s2+=r2[j]; }
            float pf = g_pf[0];
            for (int j=0;j<NBANDS;j++) gbase[i*NBANDS+j] = r1[j]/s1 + pf*(r2[j]/s2);
        }
    } else {
        int idx = blk - 81;
        int inst = idx >> 4;
        int t = idx & 15;
        int r0 = (t>>2)*64, c0 = (t&3)*64;
        const float* src; ushort_t* dst;
        if (inst < 10){
            int k = inst>>1, half = inst&1;
            src = w1  + ((size_t)k*512 + half*256)*256;
            dst = w1bt+ ((size_t)k*512 + half*256)*256;
        } else {
            int k = inst-10;
            src = gw  + (size_t)k*65536;
            dst = gwbt+ (size_t)k*65536;
        }
        int jj = tid & 63, i4 = tid >> 6;
        for (int p=0;p<16;p++){
            int i = p*4 + i4;
            tile[i][jj] = f2bu(src[(size_t)(r0+i)*256 + c0 + jj]);
        }
        __syncthreads();
        for (int p=0;p<16;p++){
            int i = p*4 + i4;
            dst[(size_t)(c0+i)*256 + r0 + jj] = tile[jj][i];
        }
    }
}

// ============ k_graph: fused per-(band,batch,i-quarter) graph pipeline ======
// R3 structure (320 blocks, 16 rows) + packed b128 staging + ys-aliased LDS.
// kb = blk % 80 so the 4 iq-siblings sit 80 apart (same XCD, share L2).
__global__ void __launch_bounds__(512) k_graph(
    const float* __restrict__ feat,
    const ushort_t* __restrict__ w1bt, const float* __restrict__ b1,
    const float* __restrict__ w2, const float* __restrict__ b2arr,
    const float* __restrict__ sbase,
    const ushort_t* __restrict__ gwbt, const float* __restrict__ gb,
    const float* __restrict__ imp_w,
    float* __restrict__ out_local,
    float* __restrict__ scalew4, float* __restrict__ impw4)
{
    int kb = blockIdx.x % 80;
    int iq = blockIdx.x / 80;
    int k  = kb >> 4;
    int b  = kb & 15;
    int i0 = iq << 4;
    int tid = threadIdx.x;
    int w = tid >> 6, lane = tid & 63, c16 = lane & 15, quad = lane >> 4;

    // Ubuf: xtb rows @264 (staging+ab), b-dyn rows @266 (dyn), ys rows @264 (gcn)
    __shared__ __align__(16) ushort_t Ubuf[64*266 + 8];
    __shared__ __align__(16) ushort_t as[16][260];   // a rows (broadcast reads)
    __shared__ __align__(16) ushort_t cs[16][72];    // comb rows
    ushort_t* ys = Ubuf;                             // aliased after dyn

    const float* src = feat + ((size_t)b*NBANDS + k)*DIM*NNODE;  // [256][64] fp32

    // early cold loads (consumed several phases later)
    int il0 = w*2, il1 = w*2 + 1;
    float sb0 = sbase[(k*NNODE + i0 + il0)*NNODE + lane];
    float sb1 = sbase[(k*NNODE + i0 + il1)*NNODE + lane];
    float sbias2 = b2arr[k];
    int col0 = w*32 + c16;
    int col1 = col0 + 16;
    float bias0 = b1[k*DIM + col0];
    float bias1 = b1[k*DIM + col1];

    // ---- staging: pack 8 bf16 per thread, ds_write_b128 ---------------------
    #pragma unroll
    for (int u = 0; u < 4; ++u){
        int t = u*512 + tid;
        int n = t & 63;
        int d0 = (t >> 6) * 8;
        short8 pk;
        #pragma unroll
        for (int i = 0; i < 8; ++i) pk[i] = (short)f2bu(src[(size_t)(d0+i)*NNODE + n]);
        *reinterpret_cast<short8*>(&Ubuf[(size_t)n*264 + d0]) = pk;
    }
    __syncthreads();

    // ---- ab GEMM: a = xt@W1a (+bias, 16 rows), b = xt@W1b (64 rows) --------
    const ushort_t* Ba = w1bt + (size_t)k*512*DIM;
    const ushort_t* Bb = Ba + 256*DIM;
    float4v z = {0.f,0.f,0.f,0.f};
    float4v aA0=z, aA1=z;
    float4v aB00=z,aB01=z,aB10=z,aB11=z,aB20=z,aB21=z,aB30=z,aB31=z;
    #pragma unroll
    for (int ks = 0; ks < 8; ++ks){
        int ko = ks*32 + quad*8;
        short8 fa = *reinterpret_cast<const short8*>(&Ubuf[(i0 + c16)*264 + ko]);
        short8 f0 = *reinterpret_cast<const short8*>(&Ubuf[( 0 + c16)*264 + ko]);
        short8 f1 = *reinterpret_cast<const short8*>(&Ubuf[(16 + c16)*264 + ko]);
        short8 f2 = *reinterpret_cast<const short8*>(&Ubuf[(32 + c16)*264 + ko]);
        short8 f3 = *reinterpret_cast<const short8*>(&Ubuf[(48 + c16)*264 + ko]);
        short8 wa0 = *reinterpret_cast<const short8*>(Ba + (size_t)col0*DIM + ko);
        short8 wa1 = *reinterpret_cast<const short8*>(Ba + (size_t)col1*DIM + ko);
        short8 wb0 = *reinterpret_cast<const short8*>(Bb + (size_t)col0*DIM + ko);
        short8 wb1 = *reinterpret_cast<const short8*>(Bb + (size_t)col1*DIM + ko);
        aA0  = MFMA(fa, wa0, aA0, 0,0,0);
        aA1  = MFMA(fa, wa1, aA1, 0,0,0);
        aB00 = MFMA(f0, wb0, aB00, 0,0,0);
        aB01 = MFMA(f0, wb1, aB01, 0,0,0);
        aB10 = MFMA(f1, wb0, aB10, 0,0,0);
        aB11 = MFMA(f1, wb1, aB11, 0,0,0);
        aB20 = MFMA(f2, wb0, aB20, 0,0,0);
        aB21 = MFMA(f2, wb1, aB21, 0,0,0);
        aB30 = MFMA(f3, wb0, aB30, 0,0,0);
        aB31 = MFMA(f3, wb1, aB31, 0,0,0);
    }
    __syncthreads();   // all xtb reads done; Ubuf reused as b-dyn region (@266)
    {
        int r0 = quad*4;
        #pragma unroll
        for (int r = 0; r < 4; ++r){
            as[r0 + r][col0] = f2bu(aA0[r] + bias0);
            as[r0 + r][col1] = f2bu(aA1[r] + bias1);
            Ubuf[( 0 + r0 + r)*266 + col0] = f2bu(aB00[r]);
            Ubuf[( 0 + r0 + r)*266 + col1] = f2bu(aB01[r]);
            Ubuf[(16 + r0 + r)*266 + col0] = f2bu(aB10[r]);
            Ubuf[(16 + r0 + r)*266 + col1] = f2bu(aB11[r]);
            Ubuf[(32 + r0 + r)*266 + col0] = f2bu(aB20[r]);
            Ubuf[(32 + r0 + r)*266 + col1] = f2bu(aB21[r]);
            Ubuf[(48 + r0 + r)*266 + col0] = f2bu(aB30[r]);
            Ubuf[(48 + r0 + r)*266 + col1] = f2bu(aB31[r]);
        }
    }
    __syncthreads();

    // ---- dyn + comb: wave owns rows 2w,2w+1; lane = j (stride-266 = free) ---
    {
        const ushort_t* bd = Ubuf + 266*lane;
        const ushort_t* a0p = &as[il0][0];
        const ushort_t* a1p = &as[il1][0];
        const float* w2p = w2 + k*DIM;           // uniform, L1/L2-hot
        float acc0 = 0.f, acc1 = 0.f;
        #pragma unroll 4
        for (int dd = 0; dd < 64; ++dd){
            unsigned int blo = *reinterpret_cast<const unsigned int*>(bd + dd*4);
            unsigned int bhi = *reinterpret_cast<const unsigned int*>(bd + dd*4 + 2);
            ushort4 a0 = *reinterpret_cast<const ushort4*>(a0p + dd*4);   // broadcast
            ushort4 a1 = *reinterpret_cast<const ushort4*>(a1p + dd*4);   // broadcast
            float4 wv  = *reinterpret_cast<const float4*>(w2p + dd*4);
            float bx = bu2f((ushort_t)(blo & 0xffffu));
            float by = bu2f((ushort_t)(blo >> 16));
            float bz = bu2f((ushort_t)(bhi & 0xffffu));
            float bq = bu2f((ushort_t)(bhi >> 16));
            acc0 += elu(bu2f(a0.x)+bx)*wv.x + elu(bu2f(a0.y)+by)*wv.y
                  + elu(bu2f(a0.z)+bz)*wv.z + elu(bu2f(a0.w)+bq)*wv.w;
            acc1 += elu(bu2f(a1.x)+bx)*wv.x + elu(bu2f(a1.y)+by)*wv.y
                  + elu(bu2f(a1.z)+bz)*wv.z + elu(bu2f(a1.w)+bq)*wv.w;
        }
        float sg0 = 1.f/(1.f + __expf(-(acc0 + sbias2)));
        float sg1 = 1.f/(1.f + __expf(-(acc1 + sbias2)));
        float val0 = sb0 + sg0;
        float val1 = sb1 + sg1;
        float m0 = val0, m1 = val1;
        for (int o=32;o>0;o>>=1){ m0 = fmaxf(m0, __shfl_xor(m0,o,64)); m1 = fmaxf(m1, __shfl_xor(m1,o,64)); }
        float e0 = __expf(val0 - m0), e1 = __expf(val1 - m1);
        float s0 = e0, s1 = e1;
        for (int o=32;o>0;o>>=1){ s0 += __shfl_xor(s0,o,64); s1 += __shfl_xor(s1,o,64); }
        cs[il0][lane] = f2bu(e0/s0);
        cs[il1][lane] = f2bu(e1/s1);
    }
    __syncthreads();   // b-rows dead; Ubuf reused as ys (@264)

    // ---- y GEMM: y[16][256] = comb[16][64] @ xt[64][256] -------------------
    {
        float4v aY0 = z, aY1 = z;
        #pragma unroll
        for (int ks = 0; ks < 2; ++ks){
            int ko = ks*32 + quad*8;
            short8 af = *reinterpret_cast<const short8*>(&cs[c16][ko]);
            const float* f0p = src + (size_t)col0*NNODE + ko;
            const float* f1p = src + (size_t)col1*NNODE + ko;
            float4 x0 = *reinterpret_cast<const float4*>(f0p);
            float4 x1 = *reinterpret_cast<const float4*>(f0p+4);
            float4 y0 = *reinterpret_cast<const float4*>(f1p);
            float4 y1 = *reinterpret_cast<const float4*>(f1p+4);
            short8 bf0, bf1;
            bf0[0]=(short)f2bu(x0.x); bf0[1]=(short)f2bu(x0.y); bf0[2]=(short)f2bu(x0.z); bf0[3]=(short)f2bu(x0.w);
            bf0[4]=(short)f2bu(x1.x); bf0[5]=(short)f2bu(x1.y); bf0[6]=(short)f2bu(x1.z); bf0[7]=(short)f2bu(x1.w);
            bf1[0]=(short)f2bu(y0.x); bf1[1]=(short)f2bu(y0.y); bf1[2]=(short)f2bu(y0.z); bf1[3]=(short)f2bu(y0.w);
            bf1[4]=(short)f2bu(y1.x); bf1[5]=(short)f2bu(y1.y); bf1[6]=(short)f2bu(y1.z); bf1[7]=(short)f2bu(y1.w);
            aY0 = MFMA(af, bf0, aY0, 0,0,0);
            aY1 = MFMA(af, bf1, aY1, 0,0,0);
        }
        #pragma unroll
        for (int r=0;r<4;++r){
            ys[(quad*4 + r)*264 + col0] = f2bu(aY0[r]);
            ys[(quad*4 + r)*264 + col1] = f2bu(aY1[r]);
        }
    }
    __syncthreads();

    // ---- gcn GEMM + fused scale/importance partial reductions --------------
    {
        float4v aG0 = z, aG1 = z;
        const ushort_t* Bg = gwbt + (size_t)k*DIM*DIM;
        #pragma unroll
        for (int ks = 0; ks < 8; ++ks){
            int ko = ks*32 + quad*8;
            short8 af = *reinterpret_cast<const short8*>(&ys[c16*264 + ko]);
            short8 g0 = *reinterpret_cast<const short8*>(Bg + (size_t)col0*DIM + ko);
            short8 g1 = *reinterpret_cast<const short8*>(Bg + (size_t)col1*DIM + ko);
            aG0 = MFMA(af, g0, aG0, 0,0,0);
            aG1 = MFMA(af, g1, aG1, 0,0,0);
        }
        int nb = i0 + quad*4;
        float iw0 = imp_w[k*NNODE + nb + 0];
        float iw1 = imp_w[k*NNODE + nb + 1];
        float iw2 = imp_w[k*NNODE + nb + 2];
        float iw3 = imp_w[k*NNODE + nb + 3];
        size_t obase = ((size_t)b*NBANDS + k)*DIM;

        float gbias0 = gb[k*DIM + col0];
        float v0 = aG0[0]+gbias0, v1 = aG0[1]+gbias0, v2 = aG0[2]+gbias0, v3 = aG0[3]+gbias0;
        *reinterpret_cast<float4*>(&out_local[(obase + col0)*NNODE + nb]) =
            make_float4(v0,v1,v2,v3);
        float s  = v0+v1+v2+v3;
        float di = v0*iw0 + v1*iw1 + v2*iw2 + v3*iw3;
        s  += __shfl_xor(s,16,64);  s  += __shfl_xor(s,32,64);
        di += __shfl_xor(di,16,64); di += __shfl_xor(di,32,64);
        if (quad == 0){
            size_t o = (size_t)iq*20480 + ((size_t)b*SEQ + k)*DIM + col0;
            scalew4[o] = s;
            impw4[o]   = di;
        }

        float gbias1 = gb[k*DIM + col1];
        v0 = aG1[0]+gbias1; v1 = aG1[1]+gbias1; v2 = aG1[2]+gbias1; v3 = aG1[3]+gbias1;
        *reinterpret_cast<float4*>(&out_local[(obase + col1)*NNODE + nb]) =
            make_float4(v0,v1,v2,v3);
        s  = v0+v1+v2+v3;
        di = v0*iw0 + v1*iw1 + v2*iw2 + v3*iw3;
        s  += __shfl_xor(s,16,64);  s  += __shfl_xor(s,32,64);
        di += __shfl_xor(di,16,64); di += __shfl_xor(di,32,64);
        if (quad == 0){
            size_t o = (size_t)iq*20480 + ((size_t)b*SEQ + k)*DIM + col1;
            scalew4[o] = s;
            impw4[o]   = di;
        }
    }
}

// ---- qkv GEMV with fused scale-partial fold --------------------------------
__global__ void __launch_bounds__(256) k_qkv_gemv(const float* __restrict__ scalew4,
                        const float* __restrict__ w, const float* __restrict__ bias,
                        float* __restrict__ out)
{
    int row = blockIdx.x / 12;
    int n0 = (blockIdx.x % 12) * 64;
    int tid = threadIdx.x;
    int c = tid & 63, s = tid >> 6;
    __shared__ float xs[DIM];
    __shared__ float part[4][64];
    xs[tid] = sum4(scalew4, (size_t)row*DIM + tid) * (1.f/64.f);
    __syncthreads();
    const float* wp = w + (size_t)(s*64)*768 + n0 + c;
    const float* xp = xs + s*64;
    float acc = 0.f;
    #pragma unroll 8
    for (int i = 0; i < 64; ++i) acc += xp[i] * wp[(size_t)i*768];
    part[s][c] = acc;
    __syncthreads();
    if (s == 0){
        out[(size_t)row*768 + n0 + c] = bias[n0+c] + part[0][c]+part[1][c]+part[2][c]+part[3][c];
    }
}

// ---- generic sliced GEMV ---------------------------------------------------
template<int COLS, int SLICES>
__global__ void __launch_bounds__(256) k_gemv(const float* __restrict__ x, const float* __restrict__ w,
                       const float* __restrict__ bias, float* __restrict__ out,
                       int K, int N, int act)
{
    int chunks = N / COLS;
    int row = blockIdx.x / chunks;
    int n0 = (blockIdx.x % chunks) * COLS;
    int c = threadIdx.x % COLS, s = threadIdx.x / COLS;
    __shared__ float xs[1024];
    __shared__ float part[SLICES][COLS];
    for (int i = threadIdx.x; i < K; i += 256) xs[i] = x[(size_t)row*K + i];
    __syncthreads();
    int klen = K / SLICES;
    const float* wp = w + (size_t)(s*klen)*N + n0 + c;
    const float* xp = xs + s*klen;
    float acc = 0.f;
    #pragma unroll 8
    for (int i = 0; i < klen; ++i) acc += xp[i] * wp[(size_t)i*N];
    part[s][c] = acc;
    __syncthreads();
    if (s == 0){
        float v = bias[n0+c];
        #pragma unroll
        for (int q=0;q<SLICES;q++) v += part[q][c];
        if (act) v = 0.5f*v*(1.f + erff(v*0.70710678118654752f));
        out[(size_t)row*N + n0 + c] = v;
    }
}

// ---- proj with fused per-row attention prologue ----------------------------
__global__ void __launch_bounds__(256) k_projattn(const float* __restrict__ qkvw,
                        const float* __restrict__ ow, const float* __restrict__ ob,
                        float* __restrict__ projw)
{
    int row = blockIdx.x / 4;            // b*SEQ + i
    int n0 = (blockIdx.x % 4) * 64;
    int b = row / SEQ, i = row % SEQ;
    int tid = threadIdx.x;
    int h = tid >> 6, l = tid & 63;
    __shared__ float xs[DIM];
    __shared__ float part[4][64];
    const float* base = qkvw + (size_t)b*SEQ*3*DIM;
    float qv = base[(size_t)i*3*DIM + h*64 + l];
    float pj[SEQ];
    #pragma unroll
    for (int j=0;j<SEQ;j++){
        float p = qv * base[(size_t)j*3*DIM + DIM + h*64 + l];
        for (int o=32;o>0;o>>=1) p += __shfl_xor(p,o,64);
        pj[j] = p * 0.125f;
    }
    float m = pj[0];
    #pragma unroll
    for (int j=1;j<SEQ;j++) m = fmaxf(m, pj[j]);
    float ssum = 0.f;
    #pragma unroll
    for (int j=0;j<SEQ;j++){ pj[j] = __expf(pj[j]-m); ssum += pj[j]; }
    float inv = 1.f/ssum;
    float o = 0.f;
    #pragma unroll
    for (int j=0;j<SEQ;j++) o += pj[j]*inv * base[(size_t)j*3*DIM + 2*DIM + h*64 + l];
    xs[tid] = o;
    __syncthreads();
    int c = tid & 63, s = tid >> 6;
    const float* wp = ow + (size_t)(s*64)*DIM + n0 + c;
    const float* xp = xs + s*64;
    float acc = 0.f;
    #pragma unroll 8
    for (int k=0;k<64;++k) acc += xp[k] * wp[(size_t)k*DIM];
    part[s][c] = acc;
    __syncthreads();
    if (s == 0){
        projw[(size_t)row*DIM + n0 + c] = ob[n0+c] + part[0][c]+part[1][c]+part[2][c]+part[3][c];
    }
}

// ---------------- block LayerNorm over 256 elems ----------------------------
__device__ __forceinline__ float block_ln(float v, int tid, float* red, float g, float bln)
{
    float s = v;
    for (int o=32;o>0;o>>=1) s += __shfl_xor(s,o,64);
    int wave = tid>>6, lane = tid&63;
    if (lane==0) red[wave] = s;
    __syncthreads();
    float mean = (red[0]+red[1]+red[2]+red[3]) * (1.f/DIM);
    float c = v - mean;
    float q = c*c;
    for (int o=32;o>0;o>>=1) q += __shfl_xor(q,o,64);
    __syncthreads();
    if (lane==0) red[wave] = q;
    __syncthreads();
    float var = (red[0]+red[1]+red[2]+red[3]) * (1.f/DIM);
    return c * rsqrtf(var + 1e-5f) * g + bln;
}

// ---- mlp1 with fused LN1 prologue (folds scale partials) -------------------
__global__ void __launch_bounds__(256) k_mlp1_ln(const float* __restrict__ projw,
                         const float* __restrict__ scalew4,
                         const float* __restrict__ ln1_g, const float* __restrict__ ln1_b,
                         const float* __restrict__ w1, const float* __restrict__ b1,
                         float* __restrict__ h1w, float* __restrict__ mhw)
{
    int row = blockIdx.x / 16;
    int n0 = (blockIdx.x % 16) * 64;
    int tid = threadIdx.x;
    __shared__ float xs[DIM];
    __shared__ float red[4];
    __shared__ float part[4][64];
    size_t basei = (size_t)row*DIM + tid;
    float sc = sum4(scalew4, basei) * (1.f/64.f);
    float v = projw[basei] + sc;
    float h = block_ln(v, tid, red, ln1_g[tid], ln1_b[tid]);
    xs[tid] = h;
    if ((blockIdx.x % 16) == 0) h1w[basei] = h;
    __syncthreads();
    int c = tid & 63, s = tid >> 6;
    const float* wp = w1 + (size_t)(s*64)*1024 + n0 + c;
    const float* xp = xs + s*64;
    float acc = 0.f;
    #pragma unroll 8
    for (int i=0;i<64;++i) acc += xp[i] * wp[(size_t)i*1024];
    part[s][c] = acc;
    __syncthreads();
    if (s == 0){
        float o = b1[n0+c] + part[0][c] + part[1][c] + part[2][c] + part[3][c];
        o = 0.5f*o*(1.f + erff(o*0.70710678118654752f));
        mhw[(size_t)row*1024 + n0 + c] = o;
    }
}

// ---- gab with fused LN2 prologue -------------------------------------------
__global__ void __launch_bounds__(256) k_gab_ln(const float* __restrict__ m2w,
                        const float* __restrict__ h1w,
                        const float* __restrict__ ln2_g, const float* __restrict__ ln2_b,
                        const float* __restrict__ gw1, const float* __restrict__ gb1,
                        float* __restrict__ sew, float* __restrict__ gaw, float* __restrict__ gbw)
{
    int row = blockIdx.x / 4;
    int n0 = (blockIdx.x % 4) * 64;
    int tid = threadIdx.x;
    __shared__ float xs[DIM];
    __shared__ float red[4];
    __shared__ float partA[4][64];
    __shared__ float partB[4][64];
    float v = m2w[(size_t)row*DIM + tid] + h1w[(size_t)row*DIM + tid];
    float h = block_ln(v, tid, red, ln2_g[tid], ln2_b[tid]);
    xs[tid] = h;
    if ((blockIdx.x % 4) == 0) sew[(size_t)row*DIM + tid] = h;
    __syncthreads();
    int c = tid & 63, s = tid >> 6;
    const float* wpA = gw1 + (size_t)(s*64)*DIM + n0 + c;
    const float* wpB = wpA + (size_t)DIM*DIM;
    const float* xp = xs + s*64;
    float aA = 0.f, aB = 0.f;
    #pragma unroll 8
    for (int i=0;i<64;++i){
        float xv = xp[i];
        aA += xv * wpA[(size_t)i*DIM];
        aB += xv * wpB[(size_t)i*DIM];
    }
    partA[s][c] = aA;
    partB[s][c] = aB;
    __syncthreads();
    if (s == 0){
        gaw[(size_t)row*DIM + n0 + c] = gb1[n0+c] + partA[0][c]+partA[1][c]+partA[2][c]+partA[3][c];
        gbw[(size_t)row*DIM + n0 + c] = partB[0][c]+partB[1][c]+partB[2][c]+partB[3][c];
    }
}

// ---- gout with fused gadj + gmix + final modulation (folds imp partials) ---
__global__ void __launch_bounds__(256) k_goutfin(const float* __restrict__ gaw,
                        const float* __restrict__ gbw,
                        const float* __restrict__ gw2, const float* __restrict__ gb2,
                        const float* __restrict__ gbase,
                        const float* __restrict__ sew,
                        const float* __restrict__ ggw, const float* __restrict__ ggb,
                        const float* __restrict__ impw4, const float* __restrict__ imp_b,
                        float* __restrict__ out0, float* __restrict__ out_gadj)
{
    int row = blockIdx.x / 4;            // b*SEQ + i
    int n0 = (blockIdx.x % 4) * 64;
    int b = row / SEQ, i = row % SEQ;
    int tid = threadIdx.x;
    int wave = tid >> 6, lane = tid & 63;
    __shared__ float dyn_s[SEQ];
    __shared__ float xs[DIM];
    __shared__ float part[4][64];
    for (int j = wave; j < SEQ; j += 4){
        const float* gar = gaw + (size_t)row*DIM;
        const float* gbr = gbw + ((size_t)b*SEQ + j)*DIM;
        float acc = 0.f;
        #pragma unroll
        for (int m=0;m<4;m++){
            int dd = lane + m*64;
            float v = gar[dd] + gbr[dd];
            acc += elu(v) * gw2[dd];
        }
        for (int o=32;o>0;o>>=1) acc += __shfl_xor(acc,o,64);
        if (lane==0) dyn_s[j] = acc;
    }
    __syncthreads();
    float gc[SEQ];
    {
        float sb2 = gb2[0];
        float m = -1e30f;
        #pragma unroll
        for (int j=0;j<SEQ;j++){
            float sg = 1.f/(1.f+__expf(-(dyn_s[j]+sb2)));
            gc[j] = gbase[i*SEQ+j] + sg;
            m = fmaxf(m, gc[j]);
        }
        float ssum=0.f;
        #pragma unroll
        for (int j=0;j<SEQ;j++){ gc[j]=__expf(gc[j]-m); ssum+=gc[j]; }
        float inv = 1.f/ssum;
        #pragma unroll
        for (int j=0;j<SEQ;j++) gc[j] *= inv;
    }
    if (n0 == 0 && tid < SEQ) out_gadj[((size_t)b*SEQ+i)*SEQ + tid] = gc[tid];
    float t = 0.f;
    #pragma unroll
    for (int j=0;j<SEQ;j++) t += gc[j]*sew[((size_t)b*SEQ + j)*DIM + tid];
    xs[tid] = t;
    __syncthreads();
    int c = tid & 63, s = tid >> 6;
    const float* wp = ggw + (size_t)(s*64)*DIM + n0 + c;
    const float* xp = xs + s*64;
    float acc = 0.f;
    #pragma unroll 8
    for (int k=0;k<64;++k) acc += xp[k] * wp[(size_t)k*DIM];
    part[s][c] = acc;
    __syncthreads();
    if (s == 0){
        float g = ggb[n0+c] + part[0][c]+part[1][c]+part[2][c]+part[3][c];
        size_t o = (size_t)row*DIM + n0 + c;
        float imps = sum4(impw4, o);
        out0[o] = g * imps + imp_b[i];
    }
}

extern "C" void kernel_launch(void* const* d_in, const int* in_sizes, int n_in,
                              void* d_out, int out_size, void* d_ws, size_t ws_size,
                              hipStream_t stream)
{
    const float* feature      = (const float*)d_in[0];
    const float* l_adj_w      = (const float*)d_in[1];
    const float* l_sim_w1     = (const float*)d_in[2];
    const float* l_sim_b1     = (const float*)d_in[3];
    const float* l_sim_w2     = (const float*)d_in[4];
    const float* l_sim_b2     = (const float*)d_in[5];
    const float* l_pos_factor = (const float*)d_in[6];
    const float* l_pos_enc    = (const float*)d_in[7];
    const float* l_gcn_w      = (const float*)d_in[8];
    const float* l_gcn_b      = (const float*)d_in[9];
    const float* g_adj_w      = (const float*)d_in[10];
    const float* g_sim_w1     = (const float*)d_in[11];
    const float* g_sim_b1     = (const float*)d_in[12];
    const float* g_sim_w2     = (const float*)d_in[13];
    const float* g_sim_b2     = (const float*)d_in[14];
    const float* g_pos_factor = (const float*)d_in[15];
    const float* g_pos_enc    = (const float*)d_in[16];
    const float* g_gcn_w      = (const float*)d_in[17];
    const float* g_gcn_b      = (const float*)d_in[18];
    const float* qkv_w        = (const float*)d_in[19];
    const float* qkv_b        = (const float*)d_in[20];
    const float* attn_ow      = (const float*)d_in[21];
    const float* attn_ob      = (const float*)d_in[22];
    const float* ln1_g        = (const float*)d_in[23];
    const float* ln1_b        = (const float*)d_in[24];
    const float* ln2_g        = (const float*)d_in[25];
    const float* ln2_b        = (const float*)d_in[26];
    const float* mlp_w1       = (const float*)d_in[27];
    const float* mlp_b1       = (const float*)d_in[28];
    const float* mlp_w2       = (const float*)d_in[29];
    const float* mlp_b2       = (const float*)d_in[30];
    const float* imp_w        = (const float*)d_in[31];
    const float* imp_b        = (const float*)d_in[32];

    float* out0      = (float*)d_out;
    float* out_gadj  = out0 + (size_t)BATCH*NBANDS*DIM;
    float* out_local = out_gadj + (size_t)BATCH*NBANDS*NBANDS;

    ushort_t* w1bt = (ushort_t*)d_ws;                               // 5*512*256
    ushort_t* gwbt = w1bt + (size_t)NBANDS*512*DIM;                 // 5*256*256
    float* fp = (float*)(gwbt + (size_t)NBANDS*DIM*DIM);
    float* sbase   = fp; fp += NBANDS*NNODE*NNODE;
    float* gbase   = fp; fp += 32;
    float* scalew4 = fp; fp += 4*BATCH*SEQ*DIM;
    float* impw4   = fp; fp += 4*BATCH*SEQ*DIM;
    float* qkvw    = fp; fp += BATCH*SEQ*3*DIM;
    float* projw   = fp; fp += BATCH*SEQ*DIM;
    float* h1w     = fp; fp += BATCH*SEQ*DIM;
    float* mhw     = fp; fp += BATCH*SEQ*4*DIM;
    float* m2w     = fp; fp += BATCH*SEQ*DIM;
    float* sew     = fp; fp += BATCH*SEQ*DIM;
    float* gaw     = fp; fp += BATCH*SEQ*DIM;
    float* gbw     = fp; fp += BATCH*SEQ*DIM;

    const int ROWS = BATCH*SEQ;   // 80

    k_head<<<321, 256, 0, stream>>>(l_adj_w, l_pos_enc, l_pos_factor,
                                    g_adj_w, g_pos_enc, g_pos_factor,
                                    sbase, gbase,
                                    l_sim_w1, l_gcn_w, w1bt, gwbt);
    k_graph<<<NBANDS*BATCH*4, 512, 0, stream>>>(feature, w1bt, l_sim_b1,
                                    l_sim_w2, l_sim_b2, sbase,
                                    gwbt, l_gcn_b, imp_w,
                                    out_local, scalew4, impw4);
    k_qkv_gemv<<<ROWS*12, 256, 0, stream>>>(scalew4, qkv_w, qkv_b, qkvw);
    k_projattn<<<ROWS*4, 256, 0, stream>>>(qkvw, attn_ow, attn_ob, projw);
    k_mlp1_ln<<<ROWS*16, 256, 0, stream>>>(projw, scalew4, ln1_g, ln1_b, mlp_w1, mlp_b1, h1w, mhw);
    k_gemv<32,8><<<ROWS*8, 256, 0, stream>>>(mhw, mlp_w2, mlp_b2, m2w, 1024, 256, 0);
    k_gab_ln<<<ROWS*4, 256, 0, stream>>>(m2w, h1w, ln2_g, ln2_b, g_sim_w1, g_sim_b1, sew, gaw, gbw);
    k_goutfin<<<ROWS*4, 256, 0, stream>>>(gaw, gbw, g_sim_w2, g_sim_b2, gbase,
                                          sew, g_gcn_w, g_gcn_b, impw4, imp_b,
                                          out0, out_gadj);
}